// Round 7
// baseline (47.235 us; speedup 1.0000x reference)
//
#include <hip/hip_runtime.h>

#define B_   16
#define C_   3
#define H_   64
#define W_   64
#define K_   32
#define S_   16
#define OH_  60
#define OW_  60
#define P_   3600
#define IMG  (C_*H_*W_)

#define KG   8                  // k's per block
#define NKG  (K_/KG)            // 4 k-groups
#define ROWS (C_*5)             // 15 (c, rh) rows per oh-stripe
#define BPAD 20                 // padded batch stride in floats (16B-aligned slots,
                                // start-banks 4*{0,5,2,7,4,1,6,3} -> uniform)
#define ROWSTRIDE (W_*BPAD)     // 1280 floats
#define XLDS (ROWS*ROWSTRIDE)   // 19200 floats = 76.8 KB

__device__ __forceinline__ float gate(float4 c, float a, float b) {
    return fmaf(c.w, a * b, fmaf(c.z, b, fmaf(c.y, a, c.x)));
}

// Single fused kernel (identical to R6). This round: launched TWICE to
// measure per-launch cost (b + T) via dur delta vs R6 — splits "kernel is
// ~20us (latency-bound)" from "graph overhead ~15us (kernel already ~8us)".
__global__ __launch_bounds__(512, 2) void logic_fused_kernel(
    const float* __restrict__ x,
    const int* __restrict__ ah, const int* __restrict__ aw, const int* __restrict__ ac,
    const int* __restrict__ bh, const int* __restrict__ bw, const int* __restrict__ bc,
    const float* __restrict__ w0, const float* __restrict__ w1,
    const float* __restrict__ w2, const float* __restrict__ w3,
    const float* __restrict__ w4,
    float* __restrict__ out)
{
    __shared__ float  xs[XLDS];
    __shared__ float4 cf[KG * 31];
    __shared__ int    bAi[KG * S_], bBi[KG * S_];

    const int oh  = blockIdx.x;
    const int kg  = blockIdx.y;
    const int tid = threadIdx.x;
    const int l   = tid & 63;
    const int wv  = tid >> 6;           // 0..7

    // ---- stage x stripe: 240 jobs (row=c*5+dh, b); 1 coalesced 256B read each
    for (int job = wv; job < ROWS * B_; job += 8) {
        int b   = job & 15;
        int row = job >> 4;             // c*5 + dh, 0..14
        int c   = row / 5, dh = row - c * 5;
        float v = x[((b * C_ + c) * H_ + (oh + dh)) * W_ + l];
        xs[row * ROWSTRIDE + l * BPAD + b] = v;
    }

    // ---- coefs (threads 0..255) and base offsets (threads 256..511)
    if (tid < 256) {
        int node = tid & 31, kk = tid >> 5;
        if (node < 31) {
            int k = kg * KG + kk;
            const float* w; int i;
            if      (node < 16) { w = w0; i = node;      }
            else if (node < 24) { w = w1; i = node - 16; }
            else if (node < 28) { w = w2; i = node - 24; }
            else if (node < 30) { w = w3; i = node - 28; }
            else                { w = w4; i = 0;         }
            const float* src = w + ((size_t)i * K_ + k) * 16;
            float lg[16];
            float m = -1e30f;
#pragma unroll
            for (int s = 0; s < 16; ++s) { lg[s] = src[s]; m = fmaxf(m, lg[s]); }
            float sum = 0.f;
#pragma unroll
            for (int s = 0; s < 16; ++s) { lg[s] = expf(lg[s] - m); sum += lg[s]; }
            float inv = 1.f / sum;
            const float M[16][4] = {
                {0,0,0,0},{0,0,0,1},{0,1,0,-1},{0,1,0,0},
                {0,0,1,-1},{0,0,1,0},{0,1,1,-2},{0,1,1,-1},
                {1,-1,-1,1},{1,-1,-1,2},{1,0,-1,0},{1,0,-1,1},
                {1,-1,0,0},{1,-1,0,1},{1,0,0,-1},{1,0,0,0}};
            float c0 = 0.f, c1 = 0.f, c2 = 0.f, c3 = 0.f;
#pragma unroll
            for (int s = 0; s < 16; ++s) {
                float pr = lg[s] * inv;
                c0 += pr * M[s][0]; c1 += pr * M[s][1];
                c2 += pr * M[s][2]; c3 += pr * M[s][3];
            }
            cf[kk * 31 + node] = make_float4(c0, c1, c2, c3);
        }
    } else {
        int i = tid - 256;              // 0..255
        int s = i & 15, kk = (i >> 4) & 7;
        int k = kg * KG + kk;
        int idx = k * (P_ * 16) + s;    // p = 0 slice -> relative offsets
        if (i < 128)
            bAi[kk * 16 + s] = (ac[idx] * 5 + ah[idx]) * ROWSTRIDE + aw[idx] * BPAD;
        else
            bBi[kk * 16 + s] = (bc[idx] * 5 + bh[idx]) * ROWSTRIDE + bw[idx] * BPAD;
    }
    __syncthreads();

    // ---- compute: wave wv -> k = kg*8 + wv
    const int k = kg * KG + wv;
    const int e = l >> 4;               // batch group (4 batches)

    float4 creg[S_];                    // leaf coefs in registers (64 VGPR)
#pragma unroll
    for (int s = 0; s < S_; ++s) creg[s] = cf[wv * 31 + s];

    int baseA[S_], baseB[S_];           // wave-uniform -> SGPR
#pragma unroll
    for (int s = 0; s < S_; ++s) {
        baseA[s] = __builtin_amdgcn_readfirstlane(bAi[wv * 16 + s]);
        baseB[s] = __builtin_amdgcn_readfirstlane(bBi[wv * 16 + s]);
    }

    const int obase = k * P_ + oh * OW_;

    for (int q = 0; q < 4; ++q) {
        int ow     = q * 16 + (l & 15);
        int ow_eff = ow < OW_ ? ow : OW_ - 1;   // helper lanes clamp (no store)
        int lo     = ow_eff * BPAD + e * 4;

        float t[4][8];                  // after fused leaf+level-1 (32 VGPR)
#pragma unroll
        for (int i = 0; i < 8; ++i) {
            float4 a0 = *(const float4*)&xs[baseA[2*i]   + lo];
            float4 b0 = *(const float4*)&xs[baseB[2*i]   + lo];
            float4 a1 = *(const float4*)&xs[baseA[2*i+1] + lo];
            float4 b1 = *(const float4*)&xs[baseB[2*i+1] + lo];
            float4 c0 = creg[2*i], c1 = creg[2*i+1];
            float4 d  = cf[wv * 31 + 16 + i];
            {
                float la = gate(c0, a0.x, b0.x), lb = gate(c1, a1.x, b1.x);
                t[0][i] = gate(d, la, lb);
            }
            {
                float la = gate(c0, a0.y, b0.y), lb = gate(c1, a1.y, b1.y);
                t[1][i] = gate(d, la, lb);
            }
            {
                float la = gate(c0, a0.z, b0.z), lb = gate(c1, a1.z, b1.z);
                t[2][i] = gate(d, la, lb);
            }
            {
                float la = gate(c0, a0.w, b0.w), lb = gate(c1, a1.w, b1.w);
                t[3][i] = gate(d, la, lb);
            }
        }
        // level 2 (nodes 24..27)
#pragma unroll
        for (int i = 0; i < 4; ++i) {
            float4 c = cf[wv * 31 + 24 + i];
#pragma unroll
            for (int j = 0; j < 4; ++j)
                t[j][i] = gate(c, t[j][2*i], t[j][2*i+1]);
        }
        // level 3 (nodes 28..29)
#pragma unroll
        for (int i = 0; i < 2; ++i) {
            float4 c = cf[wv * 31 + 28 + i];
#pragma unroll
            for (int j = 0; j < 4; ++j)
                t[j][i] = gate(c, t[j][2*i], t[j][2*i+1]);
        }
        // root (node 30) + store
        {
            float4 c = cf[wv * 31 + 30];
            if (ow < OW_) {
#pragma unroll
                for (int j = 0; j < 4; ++j) {
                    float r = gate(c, t[j][0], t[j][1]);
                    out[(size_t)(e * 4 + j) * (K_ * P_) + obase + ow] = r;
                }
            }
        }
    }
}

extern "C" void kernel_launch(void* const* d_in, const int* in_sizes, int n_in,
                              void* d_out, int out_size, void* d_ws, size_t ws_size,
                              hipStream_t stream) {
    const float* x  = (const float*)d_in[0];
    const int* ah = (const int*)d_in[1];
    const int* aw = (const int*)d_in[2];
    const int* ac = (const int*)d_in[3];
    const int* bh = (const int*)d_in[4];
    const int* bw = (const int*)d_in[5];
    const int* bc = (const int*)d_in[6];
    const float* w0 = (const float*)d_in[7];
    const float* w1 = (const float*)d_in[8];
    const float* w2 = (const float*)d_in[9];
    const float* w3 = (const float*)d_in[10];
    const float* w4 = (const float*)d_in[11];
    float* out = (float*)d_out;

    dim3 grid(OH_, NKG);
    // Launched twice on purpose (idempotent): dur delta vs R6 measures one
    // full (launch + kernel) cost, splitting kernel-time vs graph-overhead.
    logic_fused_kernel<<<grid, 512, 0, stream>>>(x, ah, aw, ac, bh, bw, bc,
                                                 w0, w1, w2, w3, w4, out);
    logic_fused_kernel<<<grid, 512, 0, stream>>>(x, ah, aw, ac, bh, bw, bc,
                                                 w0, w1, w2, w3, w4, out);
}

// Round 8
// 43.376 us; speedup vs baseline: 1.0890x; 1.0890x over previous
//
#include <hip/hip_runtime.h>

#define B_   16
#define C_   3
#define H_   64
#define W_   64
#define K_   32
#define S_   16
#define OH_  60
#define OW_  60
#define P_   3600

#define KG   4                  // k's per block (one per wave)
#define NKG  (K_/KG)            // 8 k-groups
#define ROWS (C_*5)             // 15 (c, rh) rows per oh-stripe
#define BP   8                  // batch-group size staged per block
#define ROWSTRIDE (W_*BP)       // 512 floats; bank-uniform for stride-8 reads
#define XLDS (ROWS*ROWSTRIDE)   // 7680 floats = 30.7 KB

__device__ __forceinline__ float gate(float4 c, float a, float b) {
    return fmaf(c.w, a * b, fmaf(c.z, b, fmaf(c.y, a, c.x)));
}

// Block (oh, bh, kg): stages 8 batches of the oh-stripe into LDS (30.7 KB ->
// 4 blocks/CU, ~15 waves/CU vs R6's 7.5), computes 4 k's coefs + offsets,
// evaluates the gate tree. Wave wv owns k = kg*4+wv; lane = (ow 32, e 2);
// 2 ow-halves per lane. Leaf coefs read from LDS (broadcast) to stay <=128 VGPR.
__global__ __launch_bounds__(256, 4) void logic_fused_kernel(
    const float* __restrict__ x,
    const int* __restrict__ ah, const int* __restrict__ aw, const int* __restrict__ ac,
    const int* __restrict__ bh_, const int* __restrict__ bw_, const int* __restrict__ bc_,
    const float* __restrict__ w0, const float* __restrict__ w1,
    const float* __restrict__ w2, const float* __restrict__ w3,
    const float* __restrict__ w4,
    float* __restrict__ out)
{
    __shared__ float  xs[XLDS];
    __shared__ float4 cf[KG * 31];
    __shared__ int    bAi[KG * S_], bBi[KG * S_];

    const int oh  = blockIdx.x;
    const int bh  = blockIdx.y;          // batch half: batches bh*8 .. bh*8+7
    const int kg  = blockIdx.z;
    const int tid = threadIdx.x;
    const int l   = tid & 63;
    const int wv  = tid >> 6;            // 0..3

    // ---- stage: 120 jobs (row 15 x w-octet 8); lane covers (w0=l>>3, b=l&7)
    // write banks = l mod 32 -> conflict-free; global reads: 8x 32B segments.
    {
        const int b  = l & 7;
        const int w0 = l >> 3;
        const int gb = bh * 8 + b;
        for (int job = wv; job < ROWS * 8; job += 4) {
            int wb  = job & 7;
            int row = job >> 3;          // c*5 + dh
            int c   = row / 5, dh = row - c * 5;
            int w   = w0 + 8 * wb;
            xs[row * ROWSTRIDE + w * BP + b] =
                x[((gb * C_ + c) * H_ + (oh + dh)) * W_ + w];
        }
    }

    // ---- coefs (threads 0..127) and base offsets (threads 128..255)
    if (tid < 128) {
        int node = tid & 31, kk = tid >> 5;
        if (node < 31) {
            int k = kg * KG + kk;
            const float* w; int i;
            if      (node < 16) { w = w0; i = node;      }
            else if (node < 24) { w = w1; i = node - 16; }
            else if (node < 28) { w = w2; i = node - 24; }
            else if (node < 30) { w = w3; i = node - 28; }
            else                { w = w4; i = 0;         }
            const float* src = w + ((size_t)i * K_ + k) * 16;
            float lg[16];
            float m = -1e30f;
#pragma unroll
            for (int s = 0; s < 16; ++s) { lg[s] = src[s]; m = fmaxf(m, lg[s]); }
            float sum = 0.f;
#pragma unroll
            for (int s = 0; s < 16; ++s) { lg[s] = expf(lg[s] - m); sum += lg[s]; }
            float inv = 1.f / sum;
            const float M[16][4] = {
                {0,0,0,0},{0,0,0,1},{0,1,0,-1},{0,1,0,0},
                {0,0,1,-1},{0,0,1,0},{0,1,1,-2},{0,1,1,-1},
                {1,-1,-1,1},{1,-1,-1,2},{1,0,-1,0},{1,0,-1,1},
                {1,-1,0,0},{1,-1,0,1},{1,0,0,-1},{1,0,0,0}};
            float c0 = 0.f, c1 = 0.f, c2 = 0.f, c3 = 0.f;
#pragma unroll
            for (int s = 0; s < 16; ++s) {
                float pr = lg[s] * inv;
                c0 += pr * M[s][0]; c1 += pr * M[s][1];
                c2 += pr * M[s][2]; c3 += pr * M[s][3];
            }
            cf[kk * 31 + node] = make_float4(c0, c1, c2, c3);
        }
    } else {
        int i = tid - 128;               // 0..127
        int s = i & 15;
        if (i < 64) {
            int kk = i >> 4;             // 0..3
            int k  = kg * KG + kk;
            int idx = k * (P_ * 16) + s; // p = 0 slice -> relative offsets
            bAi[kk * 16 + s] = (ac[idx] * 5 + ah[idx]) * ROWSTRIDE + aw[idx] * BP;
        } else {
            int kk = (i - 64) >> 4;
            int k  = kg * KG + kk;
            int idx = k * (P_ * 16) + s;
            bBi[kk * 16 + s] = (bc_[idx] * 5 + bh_[idx]) * ROWSTRIDE + bw_[idx] * BP;
        }
    }
    __syncthreads();

    // ---- compute: wave wv -> k = kg*4 + wv; lane = (ow 32, e 2)
    const int k   = kg * KG + wv;
    const int e   = l >> 5;              // batch quad within the 8 staged
    const int owl = l & 31;

    int baseA[S_], baseB[S_];            // wave-uniform -> SGPR
#pragma unroll
    for (int s = 0; s < S_; ++s) {
        baseA[s] = __builtin_amdgcn_readfirstlane(bAi[wv * 16 + s]);
        baseB[s] = __builtin_amdgcn_readfirstlane(bBi[wv * 16 + s]);
    }

    const float4* cfw = &cf[wv * 31];
    const int obase = k * P_ + oh * OW_;

    for (int q = 0; q < 2; ++q) {
        int ow     = q * 32 + owl;
        int ow_eff = ow < OW_ ? ow : OW_ - 1;   // helper lanes clamp (no store)
        int lo     = ow_eff * BP + e * 4;

        float t[4][8];                   // after fused leaf+level-1
#pragma unroll
        for (int i = 0; i < 8; ++i) {
            float4 a0 = *(const float4*)&xs[baseA[2*i]   + lo];
            float4 b0 = *(const float4*)&xs[baseB[2*i]   + lo];
            float4 a1 = *(const float4*)&xs[baseA[2*i+1] + lo];
            float4 b1 = *(const float4*)&xs[baseB[2*i+1] + lo];
            float4 c0 = cfw[2*i], c1 = cfw[2*i+1];
            float4 d  = cfw[16 + i];
            {
                float la = gate(c0, a0.x, b0.x), lb = gate(c1, a1.x, b1.x);
                t[0][i] = gate(d, la, lb);
            }
            {
                float la = gate(c0, a0.y, b0.y), lb = gate(c1, a1.y, b1.y);
                t[1][i] = gate(d, la, lb);
            }
            {
                float la = gate(c0, a0.z, b0.z), lb = gate(c1, a1.z, b1.z);
                t[2][i] = gate(d, la, lb);
            }
            {
                float la = gate(c0, a0.w, b0.w), lb = gate(c1, a1.w, b1.w);
                t[3][i] = gate(d, la, lb);
            }
        }
#pragma unroll
        for (int i = 0; i < 4; ++i) {
            float4 c = cfw[24 + i];
#pragma unroll
            for (int j = 0; j < 4; ++j)
                t[j][i] = gate(c, t[j][2*i], t[j][2*i+1]);
        }
#pragma unroll
        for (int i = 0; i < 2; ++i) {
            float4 c = cfw[28 + i];
#pragma unroll
            for (int j = 0; j < 4; ++j)
                t[j][i] = gate(c, t[j][2*i], t[j][2*i+1]);
        }
        {
            float4 c = cfw[30];
            if (ow < OW_) {
#pragma unroll
                for (int j = 0; j < 4; ++j) {
                    float r = gate(c, t[j][0], t[j][1]);
                    out[(size_t)(bh * 8 + e * 4 + j) * (K_ * P_) + obase + ow] = r;
                }
            }
        }
    }
}

extern "C" void kernel_launch(void* const* d_in, const int* in_sizes, int n_in,
                              void* d_out, int out_size, void* d_ws, size_t ws_size,
                              hipStream_t stream) {
    const float* x  = (const float*)d_in[0];
    const int* ah = (const int*)d_in[1];
    const int* aw = (const int*)d_in[2];
    const int* ac = (const int*)d_in[3];
    const int* bh = (const int*)d_in[4];
    const int* bw = (const int*)d_in[5];
    const int* bc = (const int*)d_in[6];
    const float* w0 = (const float*)d_in[7];
    const float* w1 = (const float*)d_in[8];
    const float* w2 = (const float*)d_in[9];
    const float* w3 = (const float*)d_in[10];
    const float* w4 = (const float*)d_in[11];
    float* out = (float*)d_out;

    dim3 grid(OH_, 2, NKG);
    logic_fused_kernel<<<grid, 256, 0, stream>>>(x, ah, aw, ac, bh, bw, bc,
                                                 w0, w1, w2, w3, w4, out);
}

// Round 9
// 31.405 us; speedup vs baseline: 1.5040x; 1.3812x over previous
//
#include <hip/hip_runtime.h>

#define B_   16
#define C_   3
#define H_   64
#define W_   64
#define K_   32
#define S_   16
#define OH_  60
#define OW_  60
#define P_   3600

#define KG   4                  // k's per block (one per wave)
#define NKG  (K_/KG)            // 8 k-groups
#define ROWS (C_*5)             // 15 (c, rh) rows per oh-stripe
#define BP   8                  // batch-group size staged per block
#define ROWSTRIDE (W_*BP)       // 512 floats
#define XLDS (ROWS*ROWSTRIDE)   // 7680 floats = 30.7 KB

// Bank-conflict fix (R8 had 12.78M conflict cycles = 50% of kernel):
// batch-half slot is XOR-swizzled by bit-2 of w, so a 16-lane read phase
// covers all 8 bank-quads exactly twice (2-way = free) instead of piling
// 4 addresses on quads {0,2,4,6}.
__device__ __forceinline__ int swz(int w, int e) { return e ^ ((w >> 2) & 1); }

// gate = c0 + c1*a + c2*b + c3*a*b = fma(fma(c3,a,c2), b, fma(c1,a,c0)) : 3 ops
__device__ __forceinline__ float gate(float4 c, float a, float b) {
    return fmaf(fmaf(c.w, a, c.z), b, fmaf(c.y, a, c.x));
}

__global__ __launch_bounds__(256, 4) void logic_fused_kernel(
    const float* __restrict__ x,
    const int* __restrict__ ah, const int* __restrict__ aw, const int* __restrict__ ac,
    const int* __restrict__ bh_, const int* __restrict__ bw_, const int* __restrict__ bc_,
    const float* __restrict__ w0, const float* __restrict__ w1,
    const float* __restrict__ w2, const float* __restrict__ w3,
    const float* __restrict__ w4,
    float* __restrict__ out)
{
    __shared__ float  xs[XLDS];
    __shared__ float4 cf[KG * 31];
    __shared__ int    bAi[KG * S_], bBi[KG * S_];

    const int oh  = blockIdx.x;
    const int bh  = blockIdx.y;          // batch half: batches bh*8 .. bh*8+7
    const int kg  = blockIdx.z;
    const int tid = threadIdx.x;
    const int l   = tid & 63;
    const int wv  = tid >> 6;            // 0..3

    // ---- stage: lane covers (w0=l>>3, b=l&7); swizzled half-slot placement
    {
        const int b  = l & 7;
        const int w0 = l >> 3;
        const int gb = bh * 8 + b;
        for (int job = wv; job < ROWS * 8; job += 4) {
            int wb  = job & 7;
            int row = job >> 3;          // c*5 + dh
            int c   = row / 5, dh = row - c * 5;
            int w   = w0 + 8 * wb;
            int bs  = b ^ (((w >> 2) & 1) << 2);   // swizzled slot
            xs[row * ROWSTRIDE + w * BP + bs] =
                x[((gb * C_ + c) * H_ + (oh + dh)) * W_ + w];
        }
    }

    // ---- coefs (threads 0..127) and base offsets (threads 128..255)
    if (tid < 128) {
        int node = tid & 31, kk = tid >> 5;
        if (node < 31) {
            int k = kg * KG + kk;
            const float* w; int i;
            if      (node < 16) { w = w0; i = node;      }
            else if (node < 24) { w = w1; i = node - 16; }
            else if (node < 28) { w = w2; i = node - 24; }
            else if (node < 30) { w = w3; i = node - 28; }
            else                { w = w4; i = 0;         }
            const float* src = w + ((size_t)i * K_ + k) * 16;
            float lg[16];
            float m = -1e30f;
#pragma unroll
            for (int s = 0; s < 16; ++s) { lg[s] = src[s]; m = fmaxf(m, lg[s]); }
            float sum = 0.f;
#pragma unroll
            for (int s = 0; s < 16; ++s) { lg[s] = expf(lg[s] - m); sum += lg[s]; }
            float inv = 1.f / sum;
            const float M[16][4] = {
                {0,0,0,0},{0,0,0,1},{0,1,0,-1},{0,1,0,0},
                {0,0,1,-1},{0,0,1,0},{0,1,1,-2},{0,1,1,-1},
                {1,-1,-1,1},{1,-1,-1,2},{1,0,-1,0},{1,0,-1,1},
                {1,-1,0,0},{1,-1,0,1},{1,0,0,-1},{1,0,0,0}};
            float c0 = 0.f, c1 = 0.f, c2 = 0.f, c3 = 0.f;
#pragma unroll
            for (int s = 0; s < 16; ++s) {
                float pr = lg[s] * inv;
                c0 += pr * M[s][0]; c1 += pr * M[s][1];
                c2 += pr * M[s][2]; c3 += pr * M[s][3];
            }
            cf[kk * 31 + node] = make_float4(c0, c1, c2, c3);
        }
    } else {
        int i = tid - 128;               // 0..127
        int s = i & 15;
        if (i < 64) {
            int kk = i >> 4;             // 0..3
            int k  = kg * KG + kk;
            int idx = k * (P_ * 16) + s; // p = 0 slice -> relative offsets
            bAi[kk * 16 + s] = (ac[idx] * 5 + ah[idx]) * ROWSTRIDE + aw[idx] * BP;
        } else {
            int kk = (i - 64) >> 4;
            int k  = kg * KG + kk;
            int idx = k * (P_ * 16) + s;
            bBi[kk * 16 + s] = (bc_[idx] * 5 + bh_[idx]) * ROWSTRIDE + bw_[idx] * BP;
        }
    }
    __syncthreads();

    // ---- compute: wave wv -> k = kg*4 + wv; lane = (ow 32, e 2)
    const int k   = kg * KG + wv;
    const int e   = l >> 5;              // batch quad within the 8 staged
    const int owl = l & 31;

    int baseA[S_], baseB[S_];            // wave-uniform -> SGPR
#pragma unroll
    for (int s = 0; s < S_; ++s) {
        baseA[s] = __builtin_amdgcn_readfirstlane(bAi[wv * 16 + s]);
        baseB[s] = __builtin_amdgcn_readfirstlane(bBi[wv * 16 + s]);
    }

    const float4* cfw = &cf[wv * 31];
    const int obase = k * P_ + oh * OW_;

    for (int q = 0; q < 2; ++q) {
        int ow     = q * 32 + owl;
        int ow_eff = ow < OW_ ? ow : OW_ - 1;   // helper lanes clamp (same-addr
                                                // broadcast -> no conflict)
        int lo     = ow_eff * BP + (swz(ow_eff, e) << 2);

        float t[4][8];                   // after fused leaf+level-1
#pragma unroll
        for (int i = 0; i < 8; ++i) {
            float4 a0 = *(const float4*)&xs[baseA[2*i]   + lo];
            float4 b0 = *(const float4*)&xs[baseB[2*i]   + lo];
            float4 a1 = *(const float4*)&xs[baseA[2*i+1] + lo];
            float4 b1 = *(const float4*)&xs[baseB[2*i+1] + lo];
            float4 c0 = cfw[2*i], c1 = cfw[2*i+1];
            float4 d  = cfw[16 + i];
            {
                float la = gate(c0, a0.x, b0.x), lb = gate(c1, a1.x, b1.x);
                t[0][i] = gate(d, la, lb);
            }
            {
                float la = gate(c0, a0.y, b0.y), lb = gate(c1, a1.y, b1.y);
                t[1][i] = gate(d, la, lb);
            }
            {
                float la = gate(c0, a0.z, b0.z), lb = gate(c1, a1.z, b1.z);
                t[2][i] = gate(d, la, lb);
            }
            {
                float la = gate(c0, a0.w, b0.w), lb = gate(c1, a1.w, b1.w);
                t[3][i] = gate(d, la, lb);
            }
        }
#pragma unroll
        for (int i = 0; i < 4; ++i) {
            float4 c = cfw[24 + i];
#pragma unroll
            for (int j = 0; j < 4; ++j)
                t[j][i] = gate(c, t[j][2*i], t[j][2*i+1]);
        }
#pragma unroll
        for (int i = 0; i < 2; ++i) {
            float4 c = cfw[28 + i];
#pragma unroll
            for (int j = 0; j < 4; ++j)
                t[j][i] = gate(c, t[j][2*i], t[j][2*i+1]);
        }
        {
            float4 c = cfw[30];
            if (ow < OW_) {
#pragma unroll
                for (int j = 0; j < 4; ++j) {
                    float r = gate(c, t[j][0], t[j][1]);
                    out[(size_t)(bh * 8 + e * 4 + j) * (K_ * P_) + obase + ow] = r;
                }
            }
        }
    }
}

extern "C" void kernel_launch(void* const* d_in, const int* in_sizes, int n_in,
                              void* d_out, int out_size, void* d_ws, size_t ws_size,
                              hipStream_t stream) {
    const float* x  = (const float*)d_in[0];
    const int* ah = (const int*)d_in[1];
    const int* aw = (const int*)d_in[2];
    const int* ac = (const int*)d_in[3];
    const int* bh = (const int*)d_in[4];
    const int* bw = (const int*)d_in[5];
    const int* bc = (const int*)d_in[6];
    const float* w0 = (const float*)d_in[7];
    const float* w1 = (const float*)d_in[8];
    const float* w2 = (const float*)d_in[9];
    const float* w3 = (const float*)d_in[10];
    const float* w4 = (const float*)d_in[11];
    float* out = (float*)d_out;

    dim3 grid(OH_, 2, NKG);
    logic_fused_kernel<<<grid, 256, 0, stream>>>(x, ah, aw, ac, bh, bw, bc,
                                                 w0, w1, w2, w3, w4, out);
}

// Round 10
// 30.807 us; speedup vs baseline: 1.5332x; 1.0194x over previous
//
#include <hip/hip_runtime.h>

#define B_   16
#define C_   3
#define H_   64
#define W_   64
#define K_   32
#define S_   16
#define OH_  60
#define OW_  60
#define P_   3600

#define KG   4                  // k's per block (one per wave)
#define NKG  (K_/KG)            // 8 k-groups
#define ROWS (C_*5)             // 15 (c, rh) rows per oh-stripe
#define BP   8                  // batch-group size staged per block
#define ROWSTRIDE (W_*BP)       // 512 floats
#define XLDS (ROWS*ROWSTRIDE)   // 7680 floats = 30.7 KB

// Bank strategy (replaces R9's XOR swizzle): LINEAR store layout (slot = b),
// and the compute-lane mapping interleaves the batch-quad in bit 0 of the
// lane (e = l&1, owl = l>>1). A 16-lane LDS phase then covers 8 consecutive
// pixels x both quads: banks (w'%4)*8 + e*4 + j -> exactly 2 dwords per bank
// (distinct addrs) = 2-way = free [m136]. Correct by construction: no
// store/read key to keep consistent.
__device__ __forceinline__ float gate(float4 c, float a, float b) {
    return fmaf(fmaf(c.w, a, c.z), b, fmaf(c.y, a, c.x));
}

__global__ __launch_bounds__(256, 4) void logic_fused_kernel(
    const float* __restrict__ x,
    const int* __restrict__ ah, const int* __restrict__ aw, const int* __restrict__ ac,
    const int* __restrict__ bh_, const int* __restrict__ bw_, const int* __restrict__ bc_,
    const float* __restrict__ w0, const float* __restrict__ w1,
    const float* __restrict__ w2, const float* __restrict__ w3,
    const float* __restrict__ w4,
    float* __restrict__ out)
{
    __shared__ float  xs[XLDS];
    __shared__ float4 cf[KG * 31];
    __shared__ int    bAi[KG * S_], bBi[KG * S_];

    const int oh  = blockIdx.x;
    const int bh  = blockIdx.y;          // batch half: batches bh*8 .. bh*8+7
    const int kg  = blockIdx.z;
    const int tid = threadIdx.x;
    const int l   = tid & 63;
    const int wv  = tid >> 6;            // 0..3

    // ---- stage: lane covers (w0=l>>3, b=l&7); LINEAR slot = b
    // store banks: phase lanes 0-15 -> 16 distinct banks, conflict-free.
    {
        const int b  = l & 7;
        const int w0 = l >> 3;
        const int gb = bh * 8 + b;
        for (int job = wv; job < ROWS * 8; job += 4) {
            int wb  = job & 7;
            int row = job >> 3;          // c*5 + dh
            int c   = row / 5, dh = row - c * 5;
            int w   = w0 + 8 * wb;
            xs[row * ROWSTRIDE + w * BP + b] =
                x[((gb * C_ + c) * H_ + (oh + dh)) * W_ + w];
        }
    }

    // ---- coefs (threads 0..127) and base offsets (threads 128..255)
    if (tid < 128) {
        int node = tid & 31, kk = tid >> 5;
        if (node < 31) {
            int k = kg * KG + kk;
            const float* w; int i;
            if      (node < 16) { w = w0; i = node;      }
            else if (node < 24) { w = w1; i = node - 16; }
            else if (node < 28) { w = w2; i = node - 24; }
            else if (node < 30) { w = w3; i = node - 28; }
            else                { w = w4; i = 0;         }
            const float* src = w + ((size_t)i * K_ + k) * 16;
            float lg[16];
            float m = -1e30f;
#pragma unroll
            for (int s = 0; s < 16; ++s) { lg[s] = src[s]; m = fmaxf(m, lg[s]); }
            float sum = 0.f;
#pragma unroll
            for (int s = 0; s < 16; ++s) { lg[s] = expf(lg[s] - m); sum += lg[s]; }
            float inv = 1.f / sum;
            const float M[16][4] = {
                {0,0,0,0},{0,0,0,1},{0,1,0,-1},{0,1,0,0},
                {0,0,1,-1},{0,0,1,0},{0,1,1,-2},{0,1,1,-1},
                {1,-1,-1,1},{1,-1,-1,2},{1,0,-1,0},{1,0,-1,1},
                {1,-1,0,0},{1,-1,0,1},{1,0,0,-1},{1,0,0,0}};
            float c0 = 0.f, c1 = 0.f, c2 = 0.f, c3 = 0.f;
#pragma unroll
            for (int s = 0; s < 16; ++s) {
                float pr = lg[s] * inv;
                c0 += pr * M[s][0]; c1 += pr * M[s][1];
                c2 += pr * M[s][2]; c3 += pr * M[s][3];
            }
            cf[kk * 31 + node] = make_float4(c0, c1, c2, c3);
        }
    } else {
        int i = tid - 128;               // 0..127
        int s = i & 15;
        if (i < 64) {
            int kk = i >> 4;             // 0..3
            int k  = kg * KG + kk;
            int idx = k * (P_ * 16) + s; // p = 0 slice -> relative offsets
            bAi[kk * 16 + s] = (ac[idx] * 5 + ah[idx]) * ROWSTRIDE + aw[idx] * BP;
        } else {
            int kk = (i - 64) >> 4;
            int k  = kg * KG + kk;
            int idx = k * (P_ * 16) + s;
            bBi[kk * 16 + s] = (bc_[idx] * 5 + bh_[idx]) * ROWSTRIDE + bw_[idx] * BP;
        }
    }
    __syncthreads();

    // ---- compute: wave wv -> k = kg*4 + wv; lane = (e = l&1, owl = l>>1)
    const int k   = kg * KG + wv;
    const int e   = l & 1;               // batch quad interleaved in lane bit 0
    const int owl = l >> 1;              // 0..31

    int baseA[S_], baseB[S_];            // wave-uniform -> SGPR
#pragma unroll
    for (int s = 0; s < S_; ++s) {
        baseA[s] = __builtin_amdgcn_readfirstlane(bAi[wv * 16 + s]);
        baseB[s] = __builtin_amdgcn_readfirstlane(bBi[wv * 16 + s]);
    }

    const float4* cfw = &cf[wv * 31];
    const int obase = k * P_ + oh * OW_;

    for (int q = 0; q < 2; ++q) {
        int ow     = q * 32 + owl;
        int ow_eff = ow < OW_ ? ow : OW_ - 1;   // helper lanes clamp (same-addr
                                                // broadcast -> no conflict)
        int lo     = ow_eff * BP + e * 4;

        float t[4][8];                   // after fused leaf+level-1
#pragma unroll
        for (int i = 0; i < 8; ++i) {
            float4 a0 = *(const float4*)&xs[baseA[2*i]   + lo];
            float4 b0 = *(const float4*)&xs[baseB[2*i]   + lo];
            float4 a1 = *(const float4*)&xs[baseA[2*i+1] + lo];
            float4 b1 = *(const float4*)&xs[baseB[2*i+1] + lo];
            float4 c0 = cfw[2*i], c1 = cfw[2*i+1];
            float4 d  = cfw[16 + i];
            {
                float la = gate(c0, a0.x, b0.x), lb = gate(c1, a1.x, b1.x);
                t[0][i] = gate(d, la, lb);
            }
            {
                float la = gate(c0, a0.y, b0.y), lb = gate(c1, a1.y, b1.y);
                t[1][i] = gate(d, la, lb);
            }
            {
                float la = gate(c0, a0.z, b0.z), lb = gate(c1, a1.z, b1.z);
                t[2][i] = gate(d, la, lb);
            }
            {
                float la = gate(c0, a0.w, b0.w), lb = gate(c1, a1.w, b1.w);
                t[3][i] = gate(d, la, lb);
            }
        }
#pragma unroll
        for (int i = 0; i < 4; ++i) {
            float4 c = cfw[24 + i];
#pragma unroll
            for (int j = 0; j < 4; ++j)
                t[j][i] = gate(c, t[j][2*i], t[j][2*i+1]);
        }
#pragma unroll
        for (int i = 0; i < 2; ++i) {
            float4 c = cfw[28 + i];
#pragma unroll
            for (int j = 0; j < 4; ++j)
                t[j][i] = gate(c, t[j][2*i], t[j][2*i+1]);
        }
        {
            float4 c = cfw[30];
            if (ow < OW_) {
#pragma unroll
                for (int j = 0; j < 4; ++j) {
                    float r = gate(c, t[j][0], t[j][1]);
                    out[(size_t)(bh * 8 + e * 4 + j) * (K_ * P_) + obase + ow] = r;
                }
            }
        }
    }
}

extern "C" void kernel_launch(void* const* d_in, const int* in_sizes, int n_in,
                              void* d_out, int out_size, void* d_ws, size_t ws_size,
                              hipStream_t stream) {
    const float* x  = (const float*)d_in[0];
    const int* ah = (const int*)d_in[1];
    const int* aw = (const int*)d_in[2];
    const int* ac = (const int*)d_in[3];
    const int* bh = (const int*)d_in[4];
    const int* bw = (const int*)d_in[5];
    const int* bc = (const int*)d_in[6];
    const float* w0 = (const float*)d_in[7];
    const float* w1 = (const float*)d_in[8];
    const float* w2 = (const float*)d_in[9];
    const float* w3 = (const float*)d_in[10];
    const float* w4 = (const float*)d_in[11];
    float* out = (float*)d_out;

    dim3 grid(OH_, 2, NKG);
    logic_fused_kernel<<<grid, 256, 0, stream>>>(x, ah, aw, ac, bh, bw, bc,
                                                 w0, w1, w2, w3, w4, out);
}